// Round 3
// baseline (276.733 us; speedup 1.0000x reference)
//
#include <hip/hip_runtime.h>
#include <stdint.h>

#define N_ 2
#define C_ 256
#define SP 512
#define H1 128
#define H2 64
#define H3 32

using f32x4 = __attribute__((ext_vector_type(4))) float;
using s16x8 = __attribute__((ext_vector_type(8))) short;

__device__ __forceinline__ uint32_t f2bf_rne(float x) {
    uint32_t u = __builtin_bit_cast(uint32_t, x);
    return (u + 0x7FFFu + ((u >> 16) & 1u)) >> 16;
}
__device__ __forceinline__ float bf2f(uint32_t h) {
    return __builtin_bit_cast(float, h << 16);
}

// A[n*SP+i][k] = sum_c points[n][c][i] * W0[c][k] + 0.5*b0[k]
__global__ __launch_bounds__(128) void k_precompA(
    const float* __restrict__ points, const float* __restrict__ W0,
    const float* __restrict__ b0, float* __restrict__ A)
{
    int ni = blockIdx.x;
    int n = ni >> 9, i = ni & (SP - 1);
    int k = threadIdx.x;
    const float* pb = points + (size_t)n * C_ * SP + i;
    float acc = 0.5f * b0[k];
#pragma unroll 8
    for (int c = 0; c < C_; ++c)
        acc = fmaf(pb[(size_t)c * SP], W0[c * H1 + k], acc);
    A[(size_t)ni * H1 + k] = acc;
}

// Split W1 (128x64) and W2 (64x32) into transposed bf16 hi/lo: WT[col][k]
__global__ __launch_bounds__(256) void k_prepW(
    const float* __restrict__ W1, const float* __restrict__ W2,
    short* __restrict__ W1Th, short* __restrict__ W1Tl,
    short* __restrict__ W2Th, short* __restrict__ W2Tl)
{
    int t = threadIdx.x;
    for (int idx = t; idx < H2 * H1; idx += 256) {       // 8192
        int col = idx >> 7, k = idx & 127;
        float wv = W1[k * H2 + col];
        uint32_t h = f2bf_rne(wv);
        W1Th[idx] = (short)h;
        W1Tl[idx] = (short)f2bf_rne(wv - bf2f(h));
    }
    for (int idx = t; idx < H3 * H2; idx += 256) {       // 2048
        int col = idx >> 6, k = idx & 63;
        float wv = W2[k * H3 + col];
        uint32_t h = f2bf_rne(wv);
        W2Th[idx] = (short)h;
        W2Tl[idx] = (short)f2bf_rne(wv - bf2f(h));
    }
}

__global__ __launch_bounds__(256) void k_main(
    const float* __restrict__ A,
    const short* __restrict__ W1Th, const short* __restrict__ W1Tl,
    const short* __restrict__ W2Th, const short* __restrict__ W2Tl,
    const float* __restrict__ b1, const float* __restrict__ b2,
    const float* __restrict__ W3, const float* __restrict__ b3,
    const float* __restrict__ heat, const float* __restrict__ mask,
    const float* __restrict__ pos,
    float* __restrict__ pred, float* __restrict__ accum)
{
    // LDS: X1hi[64][128]bf16 swz | X1lo | X2hi[64][64]bf16 swz | X2lo | X3[64][32]f32 swz | red
    __shared__ __align__(16) char smem[57344 + 64];
    constexpr int X1HI = 0, X1LO = 16384, X2HI = 32768, X2LO = 40960, X3O = 49152, RED = 57344;

    int n = blockIdx.z;
    int iBase = blockIdx.y * 8, jBase = blockIdx.x * 8;
    int t = threadIdx.x;

    // ---- build X1 = relu(Ai + Aj), split hi/lo -> swizzled LDS ----
    {
        int row = t >> 2, k0 = (t & 3) * 32;     // row 0..63 = ii*8+jj ; 32 k per thread
        int ii = row >> 3, jj = row & 7;
        const float4* Ai4 = (const float4*)(A + ((size_t)(n * SP + iBase + ii)) * H1 + k0);
        const float4* Aj4 = (const float4*)(A + ((size_t)(n * SP + jBase + jj)) * H1 + k0);
#pragma unroll
        for (int c8 = 0; c8 < 4; ++c8) {
            float4 a0 = Ai4[2 * c8], a1 = Ai4[2 * c8 + 1];
            float4 c0 = Aj4[2 * c8], c1 = Aj4[2 * c8 + 1];
            float xs[8] = {a0.x + c0.x, a0.y + c0.y, a0.z + c0.z, a0.w + c0.w,
                           a1.x + c1.x, a1.y + c1.y, a1.z + c1.z, a1.w + c1.w};
            s16x8 hv, lv;
#pragma unroll
            for (int e = 0; e < 8; ++e) {
                float x = fmaxf(xs[e], 0.0f);
                uint32_t h = f2bf_rne(x);
                hv[e] = (short)h;
                lv[e] = (short)f2bf_rne(x - bf2f(h));
            }
            int chunk = (k0 >> 3) + c8;                          // 0..15 (16B units)
            int off = row * 256 + ((chunk ^ (row & 15)) << 4);   // XOR swizzle
            *(s16x8*)(smem + X1HI + off) = hv;
            *(s16x8*)(smem + X1LO + off) = lv;
        }
    }
    __syncthreads();

    int l = t & 63, w = t >> 6;
    int lc = l & 15, kg = l >> 4;
    int arow = w * 16 + lc;

    // ---- layer 2: C1 = X1 @ W1 + b1 (3-product split bf16 MFMA) ----
    f32x4 acc[4];
#pragma unroll
    for (int cf = 0; cf < 4; ++cf) {
        float bv = b1[cf * 16 + lc];
        acc[cf] = (f32x4){bv, bv, bv, bv};
    }
#pragma unroll
    for (int ks = 0; ks < 4; ++ks) {
        int chunk = ks * 4 + kg;
        int aoff = arow * 256 + ((chunk ^ (arow & 15)) << 4);
        s16x8 ahi = *(const s16x8*)(smem + X1HI + aoff);
        s16x8 alo = *(const s16x8*)(smem + X1LO + aoff);
#pragma unroll
        for (int cf = 0; cf < 4; ++cf) {
            int boff = (cf * 16 + lc) * H1 + ks * 32 + kg * 8;
            s16x8 bhi = *(const s16x8*)(W1Th + boff);
            s16x8 blo = *(const s16x8*)(W1Tl + boff);
            acc[cf] = __builtin_amdgcn_mfma_f32_16x16x32_bf16(alo, bhi, acc[cf], 0, 0, 0);
            acc[cf] = __builtin_amdgcn_mfma_f32_16x16x32_bf16(ahi, blo, acc[cf], 0, 0, 0);
            acc[cf] = __builtin_amdgcn_mfma_f32_16x16x32_bf16(ahi, bhi, acc[cf], 0, 0, 0);
        }
    }
    // X2 = relu(C1) split -> LDS (rows belong to this wave; no barrier needed)
#pragma unroll
    for (int cf = 0; cf < 4; ++cf) {
#pragma unroll
        for (int r = 0; r < 4; ++r) {
            int row = w * 16 + kg * 4 + r;
            int col = cf * 16 + lc;
            float v = fmaxf(acc[cf][r], 0.0f);
            uint32_t h = f2bf_rne(v);
            uint32_t lo2 = f2bf_rne(v - bf2f(h));
            int off = row * 128 + (((col >> 3) ^ (row & 7)) << 4) + (col & 7) * 2;
            *(short*)(smem + X2HI + off) = (short)h;
            *(short*)(smem + X2LO + off) = (short)lo2;
        }
    }

    // ---- layer 3: C2 = X2 @ W2 + b2 ----
    f32x4 acc2[2];
#pragma unroll
    for (int cf = 0; cf < 2; ++cf) {
        float bv = b2[cf * 16 + lc];
        acc2[cf] = (f32x4){bv, bv, bv, bv};
    }
#pragma unroll
    for (int ks = 0; ks < 2; ++ks) {
        int chunk = ks * 4 + kg;
        int aoff = arow * 128 + ((chunk ^ (arow & 7)) << 4);
        s16x8 ahi = *(const s16x8*)(smem + X2HI + aoff);
        s16x8 alo = *(const s16x8*)(smem + X2LO + aoff);
#pragma unroll
        for (int cf = 0; cf < 2; ++cf) {
            int boff = (cf * 16 + lc) * H2 + ks * 32 + kg * 8;
            s16x8 bhi = *(const s16x8*)(W2Th + boff);
            s16x8 blo = *(const s16x8*)(W2Tl + boff);
            acc2[cf] = __builtin_amdgcn_mfma_f32_16x16x32_bf16(alo, bhi, acc2[cf], 0, 0, 0);
            acc2[cf] = __builtin_amdgcn_mfma_f32_16x16x32_bf16(ahi, blo, acc2[cf], 0, 0, 0);
            acc2[cf] = __builtin_amdgcn_mfma_f32_16x16x32_bf16(ahi, bhi, acc2[cf], 0, 0, 0);
        }
    }
    // X3 = relu(C2) -> LDS f32 (swizzled)
#pragma unroll
    for (int cf = 0; cf < 2; ++cf) {
#pragma unroll
        for (int r = 0; r < 4; ++r) {
            int row = w * 16 + kg * 4 + r;
            int col = cf * 16 + lc;
            float v = fmaxf(acc2[cf][r], 0.0f);
            int off = row * 128 + (((col >> 2) ^ (row & 7)) << 4) + (col & 3) * 4;
            *(float*)(smem + X3O + off) = v;
        }
    }
    __syncthreads();

    // ---- layer 4 (dot with W3) + BCE + loss reduce ----
    int p = t >> 2, part = t & 3;                 // 4 threads per pixel
    f32x4 v0 = *(const f32x4*)(smem + X3O + p * 128 + (((part * 2) ^ (p & 7)) << 4));
    f32x4 v1 = *(const f32x4*)(smem + X3O + p * 128 + (((part * 2 + 1) ^ (p & 7)) << 4));
    float4 w0 = *(const float4*)(W3 + part * 8);
    float4 w1 = *(const float4*)(W3 + part * 8 + 4);
    float z = v0[0] * w0.x;
    z = fmaf(v0[1], w0.y, z); z = fmaf(v0[2], w0.z, z); z = fmaf(v0[3], w0.w, z);
    z = fmaf(v1[0], w1.x, z); z = fmaf(v1[1], w1.y, z);
    z = fmaf(v1[2], w1.z, z); z = fmaf(v1[3], w1.w, z);
    z += __shfl_down(z, 2, 4);
    z += __shfl_down(z, 1, 4);

    float num = 0.0f, den = 0.0f;
    if (part == 0) {
        z += b3[0];
        int i = iBase + (p >> 3), j = jBase + (p & 7);
        size_t idx = ((size_t)n * SP + i) * SP + j;
        pred[idx] = z;
        float tg = heat[idx], mk = mask[idx], pm = pos[idx];
        float bce = fmaxf(z, 0.0f) - z * tg + log1pf(expf(-fabsf(z)));
        num = bce * mk * pm;
        den = pm;
    }
#pragma unroll
    for (int off = 32; off > 0; off >>= 1) {
        num += __shfl_down(num, off, 64);
        den += __shfl_down(den, off, 64);
    }
    float* rb = (float*)(smem + RED);
    if (l == 0) { rb[w] = num; rb[4 + w] = den; }
    __syncthreads();
    if (t == 0) {
        atomicAdd(&accum[0], (rb[0] + rb[1]) + (rb[2] + rb[3]));
        atomicAdd(&accum[1], (rb[4] + rb[5]) + (rb[6] + rb[7]));
    }
}

__global__ void k_final(const float* __restrict__ accum, float* __restrict__ out)
{
    out[0] = accum[0] / accum[1];
}

extern "C" void kernel_launch(void* const* d_in, const int* in_sizes, int n_in,
                              void* d_out, int out_size, void* d_ws, size_t ws_size,
                              hipStream_t stream)
{
    const float* points = (const float*)d_in[0];
    const float* heat   = (const float*)d_in[1];
    const float* mask   = (const float*)d_in[2];
    const float* pos    = (const float*)d_in[3];
    const float* W0     = (const float*)d_in[4];
    const float* b0     = (const float*)d_in[5];
    const float* W1     = (const float*)d_in[6];
    const float* b1     = (const float*)d_in[7];
    const float* W2     = (const float*)d_in[8];
    const float* b2     = (const float*)d_in[9];
    const float* W3     = (const float*)d_in[10];
    const float* b3     = (const float*)d_in[11];

    float* pred = (float*)d_out;                        // (2,512,512)
    float* loss = pred + (size_t)N_ * SP * SP;          // scalar

    char* ws = (char*)d_ws;
    float* accum = (float*)ws;                          // [0]=num,[1]=den
    float* A     = (float*)(ws + 256);                  // 1024*128 f32 = 512 KiB
    short* W1Th  = (short*)(ws + 256 + 524288);         // 16 KiB
    short* W1Tl  = (short*)(ws + 256 + 524288 + 16384);
    short* W2Th  = (short*)(ws + 256 + 524288 + 32768); // 4 KiB
    short* W2Tl  = (short*)(ws + 256 + 524288 + 36864);

    hipMemsetAsync(d_ws, 0, 256, stream);
    k_prepW<<<1, 256, 0, stream>>>(W1, W2, W1Th, W1Tl, W2Th, W2Tl);
    k_precompA<<<N_ * SP, H1, 0, stream>>>(points, W0, b0, A);
    k_main<<<dim3(SP / 8, SP / 8, N_), 256, 0, stream>>>(
        A, W1Th, W1Tl, W2Th, W2Tl, b1, b2, W3, b3, heat, mask, pos, pred, accum);
    k_final<<<1, 1, 0, stream>>>(accum, loss);
}

// Round 4
// 127.311 us; speedup vs baseline: 2.1737x; 2.1737x over previous
//
#include <hip/hip_runtime.h>
#include <stdint.h>

#define N_ 2
#define C_ 256
#define SP 512
#define H1 128
#define H2 64
#define H3 32

using f32x4 = __attribute__((ext_vector_type(4))) float;
using s16x8 = __attribute__((ext_vector_type(8))) short;

__device__ __forceinline__ uint32_t f2bf_rne(float x) {
    uint32_t u = __builtin_bit_cast(uint32_t, x);
    return (u + 0x7FFFu + ((u >> 16) & 1u)) >> 16;
}
__device__ __forceinline__ float bf2f(uint32_t h) {
    return __builtin_bit_cast(float, h << 16);
}

// A[n*SP+i][k] = sum_c points[n][c][i] * W0[c][k] + 0.5*b0[k]
__global__ __launch_bounds__(128) void k_precompA(
    const float* __restrict__ points, const float* __restrict__ W0,
    const float* __restrict__ b0, float* __restrict__ A)
{
    int ni = blockIdx.x;
    int n = ni >> 9, i = ni & (SP - 1);
    int k = threadIdx.x;
    const float* pb = points + (size_t)n * C_ * SP + i;
    float acc = 0.5f * b0[k];
#pragma unroll 8
    for (int c = 0; c < C_; ++c)
        acc = fmaf(pb[(size_t)c * SP], W0[c * H1 + k], acc);
    A[(size_t)ni * H1 + k] = acc;
}

// Split W1 (128x64) and W2 (64x32) into transposed bf16 hi/lo: WT[col][k]
__global__ __launch_bounds__(256) void k_prepW(
    const float* __restrict__ W1, const float* __restrict__ W2,
    short* __restrict__ W1Th, short* __restrict__ W1Tl,
    short* __restrict__ W2Th, short* __restrict__ W2Tl)
{
    int t0 = blockIdx.x * 256 + threadIdx.x;
    int stride = gridDim.x * 256;
    for (int idx = t0; idx < H2 * H1; idx += stride) {
        int col = idx >> 7, k = idx & 127;
        float wv = W1[k * H2 + col];
        uint32_t h = f2bf_rne(wv);
        W1Th[idx] = (short)h;
        W1Tl[idx] = (short)f2bf_rne(wv - bf2f(h));
    }
    for (int idx = t0; idx < H3 * H2; idx += stride) {
        int col = idx >> 6, k = idx & 63;
        float wv = W2[k * H3 + col];
        uint32_t h = f2bf_rne(wv);
        W2Th[idx] = (short)h;
        W2Tl[idx] = (short)f2bf_rne(wv - bf2f(h));
    }
}

// 16x16 pixel tile per block; 512 thr / 8 waves; wave w owns rows w*32..w*32+31
// (pixel p = w*32 + m*16 + lc  ->  i = iBase+2w+m (uniform/wave), j = jBase+lc).
// Symmetric trick: pred[i][j]==pred[j][i]; only bj>=bi blocks run; bj>bi also
// emit the mirrored BCE/stores. No __syncthreads until the loss reduce.
__global__ __launch_bounds__(512, 4) void k_main(
    const float* __restrict__ A,
    const short* __restrict__ W1Th, const short* __restrict__ W1Tl,
    const short* __restrict__ W2Th, const short* __restrict__ W2Tl,
    const float* __restrict__ b1, const float* __restrict__ b2,
    const float* __restrict__ W3, const float* __restrict__ b3,
    const float* __restrict__ heat, const float* __restrict__ mask,
    const float* __restrict__ pos,
    float* __restrict__ pred, float* __restrict__ accum)
{
    int bi = blockIdx.y, bj = blockIdx.x;
    if (bj < bi) return;
    bool diag = (bi == bj);
    int n = blockIdx.z;
    int iBase = bi * 16, jBase = bj * 16;

    // per-wave private X2 staging (wave w: hi at w*4096, lo at 32768+w*4096)
    __shared__ __align__(16) char smem[65536 + 64];

    int t = threadIdx.x;
    int l = t & 63, w = t >> 6;
    int lc = l & 15, kg = l >> 4;

    const float* Abase = A + (size_t)n * SP * H1;
    const float* Aj_row = Abase + (size_t)(jBase + lc) * H1;

    // ---- layer 2: C1 = relu(Ai+Aj) @ W1 + b1, A-frags built in registers ----
    f32x4 acc[2][4];
#pragma unroll
    for (int m = 0; m < 2; ++m)
#pragma unroll
        for (int cf = 0; cf < 4; ++cf) {
            float bv = b1[cf * 16 + lc];
            acc[m][cf] = (f32x4){bv, bv, bv, bv};
        }

#pragma unroll
    for (int ks = 0; ks < 4; ++ks) {
        s16x8 bhi[4], blo[4];
#pragma unroll
        for (int cf = 0; cf < 4; ++cf) {
            int boff = (cf * 16 + lc) * H1 + ks * 32 + kg * 8;
            bhi[cf] = *(const s16x8*)(W1Th + boff);
            blo[cf] = *(const s16x8*)(W1Tl + boff);
        }
        const float* aj_p = Aj_row + ks * 32 + kg * 8;
        f32x4 aj0 = *(const f32x4*)(aj_p);
        f32x4 aj1 = *(const f32x4*)(aj_p + 4);
#pragma unroll
        for (int m = 0; m < 2; ++m) {
            const float* ai_p = Abase + (size_t)(iBase + 2 * w + m) * H1 + ks * 32 + kg * 8;
            f32x4 ai0 = *(const f32x4*)(ai_p);
            f32x4 ai1 = *(const f32x4*)(ai_p + 4);
            s16x8 ahi, alo;
#pragma unroll
            for (int e = 0; e < 8; ++e) {
                float s = (e < 4 ? ai0[e] : ai1[e - 4]) + (e < 4 ? aj0[e] : aj1[e - 4]);
                float x = fmaxf(s, 0.0f);
                uint32_t u = __builtin_bit_cast(uint32_t, x);
                uint32_t h = u & 0xFFFF0000u;            // trunc hi
                float lof = x - __builtin_bit_cast(float, h);
                ahi[e] = (short)(h >> 16);
                alo[e] = (short)f2bf_rne(lof);           // rne lo
            }
#pragma unroll
            for (int cf = 0; cf < 4; ++cf) {
                acc[m][cf] = __builtin_amdgcn_mfma_f32_16x16x32_bf16(alo, bhi[cf], acc[m][cf], 0, 0, 0);
                acc[m][cf] = __builtin_amdgcn_mfma_f32_16x16x32_bf16(ahi, blo[cf], acc[m][cf], 0, 0, 0);
                acc[m][cf] = __builtin_amdgcn_mfma_f32_16x16x32_bf16(ahi, bhi[cf], acc[m][cf], 0, 0, 0);
            }
        }
    }

    // ---- X2 = relu(C1) hi/lo -> per-wave LDS (16B-granule XOR swizzle) ----
    char* myhi = smem + w * 4096;
    char* mylo = smem + 32768 + w * 4096;
#pragma unroll
    for (int m = 0; m < 2; ++m)
#pragma unroll
        for (int cf = 0; cf < 4; ++cf)
#pragma unroll
            for (int r = 0; r < 4; ++r) {
                int row = m * 16 + kg * 4 + r;
                int col = cf * 16 + lc;
                int g = col >> 3;
                int off = row * 128 + ((g ^ (row & 7)) << 4) + (col & 7) * 2;
                float v = fmaxf(acc[m][cf][r], 0.0f);
                uint32_t u = __builtin_bit_cast(uint32_t, v);
                uint32_t h = u & 0xFFFF0000u;
                *(short*)(myhi + off) = (short)(h >> 16);
                *(short*)(mylo + off) = (short)f2bf_rne(v - __builtin_bit_cast(float, h));
            }

    // ---- layer 3: C2 = X2 @ W2 + b2 (same-wave LDS, no barrier) ----
    f32x4 acc2[2][2];
#pragma unroll
    for (int m = 0; m < 2; ++m)
#pragma unroll
        for (int cf = 0; cf < 2; ++cf) {
            float bv = b2[cf * 16 + lc];
            acc2[m][cf] = (f32x4){bv, bv, bv, bv};
        }
#pragma unroll
    for (int ks = 0; ks < 2; ++ks) {
        s16x8 bhi2[2], blo2[2];
#pragma unroll
        for (int cf = 0; cf < 2; ++cf) {
            int boff = (cf * 16 + lc) * H2 + ks * 32 + kg * 8;
            bhi2[cf] = *(const s16x8*)(W2Th + boff);
            blo2[cf] = *(const s16x8*)(W2Tl + boff);
        }
#pragma unroll
        for (int m = 0; m < 2; ++m) {
            int row = m * 16 + lc;
            int g = ks * 4 + kg;
            int off = row * 128 + ((g ^ (row & 7)) << 4);
            s16x8 ahi = *(const s16x8*)(myhi + off);
            s16x8 alo = *(const s16x8*)(mylo + off);
#pragma unroll
            for (int cf = 0; cf < 2; ++cf) {
                acc2[m][cf] = __builtin_amdgcn_mfma_f32_16x16x32_bf16(alo, bhi2[cf], acc2[m][cf], 0, 0, 0);
                acc2[m][cf] = __builtin_amdgcn_mfma_f32_16x16x32_bf16(ahi, blo2[cf], acc2[m][cf], 0, 0, 0);
                acc2[m][cf] = __builtin_amdgcn_mfma_f32_16x16x32_bf16(ahi, bhi2[cf], acc2[m][cf], 0, 0, 0);
            }
        }
    }

    // ---- layer 4 in-register + BCE (+ mirrored pixel when off-diagonal) ----
    float w3a = W3[lc], w3b = W3[16 + lc];
    float b3v = b3[0];
    float num = 0.0f, den = 0.0f;
#pragma unroll
    for (int m = 0; m < 2; ++m) {
        float zr0 = fmaxf(acc2[m][0][0], 0.0f) * w3a + fmaxf(acc2[m][1][0], 0.0f) * w3b;
        float zr1 = fmaxf(acc2[m][0][1], 0.0f) * w3a + fmaxf(acc2[m][1][1], 0.0f) * w3b;
        float zr2 = fmaxf(acc2[m][0][2], 0.0f) * w3a + fmaxf(acc2[m][1][2], 0.0f) * w3b;
        float zr3 = fmaxf(acc2[m][0][3], 0.0f) * w3a + fmaxf(acc2[m][1][3], 0.0f) * w3b;
#pragma unroll
        for (int off = 1; off < 16; off <<= 1) {   // reduce across lc within kg-group
            zr0 += __shfl_xor(zr0, off, 64);
            zr1 += __shfl_xor(zr1, off, 64);
            zr2 += __shfl_xor(zr2, off, 64);
            zr3 += __shfl_xor(zr3, off, 64);
        }
        float zsel = zr0;
        zsel = (lc == 1) ? zr1 : zsel;
        zsel = (lc == 2) ? zr2 : zsel;
        zsel = (lc == 3) ? zr3 : zsel;
        if (lc < 4) {
            float z = zsel + b3v;
            int i = iBase + 2 * w + m;
            int j = jBase + kg * 4 + lc;
            size_t idx = ((size_t)n * SP + i) * SP + j;
            pred[idx] = z;
            float zbase = fmaxf(z, 0.0f) + __logf(1.0f + __expf(-fabsf(z)));
            float tg = heat[idx], mk = mask[idx], pm = pos[idx];
            num += (zbase - z * tg) * mk * pm;
            den += pm;
            if (!diag) {
                size_t idx2 = ((size_t)n * SP + j) * SP + i;
                pred[idx2] = z;
                float tg2 = heat[idx2], mk2 = mask[idx2], pm2 = pos[idx2];
                num += (zbase - z * tg2) * mk2 * pm2;
                den += pm2;
            }
        }
    }

    // ---- loss reduction: wave shuffle -> LDS -> one atomic pair per block ----
#pragma unroll
    for (int off = 32; off > 0; off >>= 1) {
        num += __shfl_down(num, off, 64);
        den += __shfl_down(den, off, 64);
    }
    float* rb = (float*)(smem + 65536);
    if (l == 0) { rb[w] = num; rb[8 + w] = den; }
    __syncthreads();
    if (t == 0) {
        float sn = 0.0f, sd = 0.0f;
#pragma unroll
        for (int q = 0; q < 8; ++q) { sn += rb[q]; sd += rb[8 + q]; }
        atomicAdd(&accum[0], sn);
        atomicAdd(&accum[1], sd);
    }
}

__global__ void k_final(const float* __restrict__ accum, float* __restrict__ out)
{
    out[0] = accum[0] / accum[1];
}

extern "C" void kernel_launch(void* const* d_in, const int* in_sizes, int n_in,
                              void* d_out, int out_size, void* d_ws, size_t ws_size,
                              hipStream_t stream)
{
    const float* points = (const float*)d_in[0];
    const float* heat   = (const float*)d_in[1];
    const float* mask   = (const float*)d_in[2];
    const float* pos    = (const float*)d_in[3];
    const float* W0     = (const float*)d_in[4];
    const float* b0     = (const float*)d_in[5];
    const float* W1     = (const float*)d_in[6];
    const float* b1     = (const float*)d_in[7];
    const float* W2     = (const float*)d_in[8];
    const float* b2     = (const float*)d_in[9];
    const float* W3     = (const float*)d_in[10];
    const float* b3     = (const float*)d_in[11];

    float* pred = (float*)d_out;                        // (2,512,512)
    float* loss = pred + (size_t)N_ * SP * SP;          // scalar

    char* ws = (char*)d_ws;
    float* accum = (float*)ws;                          // [0]=num,[1]=den
    float* A     = (float*)(ws + 256);                  // 1024*128 f32 = 512 KiB
    short* W1Th  = (short*)(ws + 256 + 524288);
    short* W1Tl  = (short*)(ws + 256 + 524288 + 16384);
    short* W2Th  = (short*)(ws + 256 + 524288 + 32768);
    short* W2Tl  = (short*)(ws + 256 + 524288 + 36864);

    hipMemsetAsync(d_ws, 0, 256, stream);
    k_prepW<<<8, 256, 0, stream>>>(W1, W2, W1Th, W1Tl, W2Th, W2Tl);
    k_precompA<<<N_ * SP, H1, 0, stream>>>(points, W0, b0, A);
    k_main<<<dim3(SP / 16, SP / 16, N_), 512, 0, stream>>>(
        A, W1Th, W1Tl, W2Th, W2Tl, b1, b2, W3, b3, heat, mask, pos, pred, accum);
    k_final<<<1, 1, 0, stream>>>(accum, loss);
}